// Round 2
// baseline (829.795 us; speedup 1.0000x reference)
//
#include <hip/hip_runtime.h>
#include <math.h>

#define NTOT 65536
#define DD 256
#define KK 64

// ws layout in floats:
// [CS_OFF .. +131072)  : cos/sin table, 65536 float2 (cos(2pi m/N), sin(2pi m/N))
// [XRE_OFF .. +16384)  : Re(x_low)[k][d]
// [XIM_OFF .. +16384)  : Im(x_low)[k][d]
// [A_OFF  .. +16384)   : A[k][f] = s_k * Re(out_low)   (s_0=1, s_k=2)
// [BC_OFF .. +16384)   : B[k][f] = -s_k * Im(out_low)
// [PART_OFF .. )       : DFT partials, nchunk * 64 * 256 float2
#define CS_OFF    0
#define XRE_OFF   131072
#define XIM_OFF   147456
#define A_OFF     163840
#define BC_OFF    180224
#define PART_OFF  196608

__global__ void gen_cs(float2* __restrict__ cs) {
    const int m = blockIdx.x * 256 + threadIdx.x;
    const float ang = (float)m * 9.587379924285257e-05f;  // 2*pi/65536
    float s, c;
    sincosf(ang, &s, &c);
    cs[m] = make_float2(c, s);
}

__global__ void init_ab(const float* __restrict__ B_low,
                        float* __restrict__ A, float* __restrict__ Bc) {
    const int k = blockIdx.x, f = threadIdx.x;
    const float sc = (k == 0) ? 1.f : 2.f;
    A[k * DD + f]  =  sc * B_low[(k * DD + f) * 2];
    Bc[k * DD + f] = -sc * B_low[(k * DD + f) * 2 + 1];
}

// Each block: one n-chunk (clen rows), one k-half (32 modes), all 256 d.
// acc_re[k] += x * cos(theta); acc_im[k] -= x * sin(theta); theta = 2pi*k*n/N
__global__ __launch_bounds__(256) void dft_partial(
        const float* __restrict__ x, const float2* __restrict__ cs,
        float2* __restrict__ part, int clen) {
    const int chunk = blockIdx.x;
    const int kb = blockIdx.y * 32;
    const int d = threadIdx.x;
    float ar[32], ai[32];
#pragma unroll
    for (int i = 0; i < 32; ++i) { ar[i] = 0.f; ai[i] = 0.f; }
    const int n0 = chunk * clen;
    for (int nn = 0; nn < clen; ++nn) {
        const int n = n0 + nn;
        const float xv = x[(size_t)n * DD + d];
#pragma unroll
        for (int kk = 0; kk < 32; ++kk) {
            const int m = ((kb + kk) * n) & (NTOT - 1);
            const float2 t = cs[m];
            ar[kk] = fmaf(xv, t.x, ar[kk]);
            ai[kk] = fmaf(-xv, t.y, ai[kk]);
        }
    }
#pragma unroll
    for (int kk = 0; kk < 32; ++kk) {
        part[(size_t)(chunk * KK + kb + kk) * DD + d] = make_float2(ar[kk], ai[kk]);
    }
}

__global__ void dft_reduce(const float2* __restrict__ part,
                           float* __restrict__ xre, float* __restrict__ xim,
                           int nchunk) {
    const int k = blockIdx.x;
    const int d = blockIdx.y * 64 + threadIdx.x;  // 64 threads
    float sr = 0.f, si = 0.f;
#pragma unroll 8
    for (int c = 0; c < nchunk; ++c) {
        const float2 p = part[(size_t)(c * KK + k) * DD + d];
        sr += p.x; si += p.y;
    }
    xre[k * DD + d] = sr * (1.f / NTOT);
    xim[k * DD + d] = si * (1.f / NTOT);
}

// out_low[k,f] = sum_d x_low[k,d] * Wc[k,d,f]  (+ Bc, already in init)
// A += s*Re, B += -s*Im  via atomics over 4 d-chunks
__global__ __launch_bounds__(256) void mode_mix(
        const float* __restrict__ P_low,
        const float* __restrict__ xre, const float* __restrict__ xim,
        float* __restrict__ A, float* __restrict__ Bc) {
    const int k = blockIdx.x;
    const int dc = blockIdx.y;  // 0..3
    const int f = threadIdx.x;
    const float2* __restrict__ P2 = (const float2*)P_low;
    float ar = 0.f, ai = 0.f;
#pragma unroll 4
    for (int dd = 0; dd < 64; ++dd) {
        const int d = dc * 64 + dd;
        const float xr = xre[k * DD + d];
        const float xi = xim[k * DD + d];
        const float2 w = P2[(size_t)(k * DD + d) * DD + f];
        ar = fmaf(xr, w.x, ar); ar = fmaf(-xi, w.y, ar);
        ai = fmaf(xr, w.y, ai); ai = fmaf(xi, w.x, ai);
    }
    const float sc = (k == 0) ? 1.f : 2.f;
    atomicAdd(&A[k * DD + f], sc * ar);
    atomicAdd(&Bc[k * DD + f], -sc * ai);
}

// Fused: out[n,f] = sin(0.2*( x[n,:]@W[:,f] + Bias[f]
//                           + sum_k A[k,f]*cos + B[k,f]*sin ))
// Block: 64 n x 256 f. Thread: 8n x 8f register tile.
__global__ __launch_bounds__(256) void fno_out(
        const float* __restrict__ x, const float* __restrict__ W,
        const float* __restrict__ Bias, const float2* __restrict__ cs,
        const float* __restrict__ A, const float* __restrict__ Bc,
        float* __restrict__ out) {
    const int tf = threadIdx.x & 31;
    const int tn = threadIdx.x >> 5;
    const int f0 = tf * 8;
    const int n0 = blockIdx.x * 64 + tn * 8;

    float acc[8][8];
#pragma unroll
    for (int i = 0; i < 8; ++i) {
#pragma unroll
        for (int j = 0; j < 8; ++j) acc[i][j] = 0.f;
    }

    const float4* __restrict__ W4 = (const float4*)W;
    for (int d = 0; d < DD; ++d) {
        float xv[8];
#pragma unroll
        for (int i = 0; i < 8; ++i) xv[i] = x[(size_t)(n0 + i) * DD + d];
        const float4 wa = W4[(d * DD + f0) >> 2];
        const float4 wb = W4[((d * DD + f0) >> 2) + 1];
        const float w[8] = {wa.x, wa.y, wa.z, wa.w, wb.x, wb.y, wb.z, wb.w};
#pragma unroll
        for (int i = 0; i < 8; ++i) {
#pragma unroll
            for (int j = 0; j < 8; ++j) acc[i][j] = fmaf(xv[i], w[j], acc[i][j]);
        }
    }

    const float4* __restrict__ A4 = (const float4*)A;
    const float4* __restrict__ B4 = (const float4*)Bc;
#pragma unroll 1
    for (int k = 0; k < KK; ++k) {
        const float4 a0 = A4[(k * DD + f0) >> 2];
        const float4 a1 = A4[((k * DD + f0) >> 2) + 1];
        const float4 b0 = B4[(k * DD + f0) >> 2];
        const float4 b1 = B4[((k * DD + f0) >> 2) + 1];
        const float av[8] = {a0.x, a0.y, a0.z, a0.w, a1.x, a1.y, a1.z, a1.w};
        const float bv[8] = {b0.x, b0.y, b0.z, b0.w, b1.x, b1.y, b1.z, b1.w};
#pragma unroll
        for (int i = 0; i < 8; ++i) {
            const int m = (k * (n0 + i)) & (NTOT - 1);
            const float2 t = cs[m];
#pragma unroll
            for (int j = 0; j < 8; ++j) {
                acc[i][j] = fmaf(t.x, av[j], acc[i][j]);
                acc[i][j] = fmaf(t.y, bv[j], acc[i][j]);
            }
        }
    }

    const float4 bia = ((const float4*)Bias)[f0 >> 2];
    const float4 bib = ((const float4*)Bias)[(f0 >> 2) + 1];
    const float bi[8] = {bia.x, bia.y, bia.z, bia.w, bib.x, bib.y, bib.z, bib.w};
#pragma unroll
    for (int i = 0; i < 8; ++i) {
        float o[8];
#pragma unroll
        for (int j = 0; j < 8; ++j) o[j] = __sinf(0.2f * (acc[i][j] + bi[j]));
        float4* op = (float4*)(out + (size_t)(n0 + i) * DD + f0);
        op[0] = make_float4(o[0], o[1], o[2], o[3]);
        op[1] = make_float4(o[4], o[5], o[6], o[7]);
    }
}

extern "C" void kernel_launch(void* const* d_in, const int* in_sizes, int n_in,
                              void* d_out, int out_size, void* d_ws, size_t ws_size,
                              hipStream_t stream) {
    const float* x     = (const float*)d_in[0];
    const float* P_low = (const float*)d_in[1];
    const float* B_low = (const float*)d_in[2];
    const float* W     = (const float*)d_in[3];
    const float* Bias  = (const float*)d_in[4];
    float* out = (float*)d_out;
    float* ws  = (float*)d_ws;

    float2* cs   = (float2*)(ws + CS_OFF);
    float*  xre  = ws + XRE_OFF;
    float*  xim  = ws + XIM_OFF;
    float*  A    = ws + A_OFF;
    float*  Bc   = ws + BC_OFF;
    float2* part = (float2*)(ws + PART_OFF);

    // Shrink chunk count if workspace is small (deterministic per call).
    int nchunk = 256;
    while ((size_t)(PART_OFF + (size_t)nchunk * KK * DD * 2) * 4 > ws_size && nchunk > 32)
        nchunk >>= 1;
    const int clen = NTOT / nchunk;

    gen_cs<<<NTOT / 256, 256, 0, stream>>>(cs);
    init_ab<<<KK, DD, 0, stream>>>(B_low, A, Bc);
    dft_partial<<<dim3(nchunk, 2), 256, 0, stream>>>(x, cs, part, clen);
    dft_reduce<<<dim3(KK, 4), 64, 0, stream>>>(part, xre, xim, nchunk);
    mode_mix<<<dim3(KK, 4), 256, 0, stream>>>(P_low, xre, xim, A, Bc);
    fno_out<<<NTOT / 64, 256, 0, stream>>>(x, W, Bias, cs, A, Bc, out);
}